// Round 1
// baseline (236.694 us; speedup 1.0000x reference)
//
#include <hip/hip_runtime.h>

#define DIM    2048
#define SEQ    4096
#define BATCH  4
#define KW     4
#define TCHUNK 16

// One thread: 4 consecutive channels (float4) x TCHUNK timesteps, register
// sliding window for the causal K=4 stencil. d4 innermost -> coalesced.
__global__ __launch_bounds__(256) void ShortConv1D_78855599554935_kernel(
    const float* __restrict__ x, const float* __restrict__ w,
    const float* __restrict__ bias, float* __restrict__ out)
{
    constexpr int D4 = DIM / 4;        // 512 float4 columns
    constexpr int NT = SEQ / TCHUNK;   // 256 time chunks

    int idx  = blockIdx.x * blockDim.x + threadIdx.x;
    int d4   = idx % D4;
    int rest = idx / D4;
    int tc   = rest % NT;
    int bb   = rest / NT;

    const float4* __restrict__ x4 = (const float4*)x;
    const float4* __restrict__ w4 = (const float4*)w;
    const float4* __restrict__ b4 = (const float4*)bias;
    float4* __restrict__ o4 = (float4*)out;

    // weight rows for channels d = 4*d4 + j  (w is [D,K] row-major, K=4 -> one float4/row)
    float4 w0 = w4[d4 * 4 + 0];
    float4 w1 = w4[d4 * 4 + 1];
    float4 w2 = w4[d4 * 4 + 2];
    float4 w3 = w4[d4 * 4 + 3];
    float4 bv = b4[d4];

    long base = ((long)bb * SEQ + (long)tc * TCHUNK) * D4 + d4;  // in float4 units

    float4 xm3, xm2, xm1;
    if (tc > 0) {                       // wave-uniform branch
        xm3 = x4[base - 3 * D4];
        xm2 = x4[base - 2 * D4];
        xm1 = x4[base - 1 * D4];
    } else {
        xm3 = make_float4(0.f, 0.f, 0.f, 0.f);
        xm2 = xm3;
        xm1 = xm3;
    }

#pragma unroll
    for (int t = 0; t < TCHUNK; ++t) {
        float4 xc = x4[base + t * D4];
        float4 r;
        // out[t] = b + w[:,0]*x[t-3] + w[:,1]*x[t-2] + w[:,2]*x[t-1] + w[:,3]*x[t]
        r.x = bv.x + w0.x * xm3.x + w0.y * xm2.x + w0.z * xm1.x + w0.w * xc.x;
        r.y = bv.y + w1.x * xm3.y + w1.y * xm2.y + w1.z * xm1.y + w1.w * xc.y;
        r.z = bv.z + w2.x * xm3.z + w2.y * xm2.z + w2.z * xm1.z + w2.w * xc.z;
        r.w = bv.w + w3.x * xm3.w + w3.y * xm2.w + w3.z * xm1.w + w3.w * xc.w;
        o4[base + t * D4] = r;
        xm3 = xm2; xm2 = xm1; xm1 = xc;
    }
}

extern "C" void kernel_launch(void* const* d_in, const int* in_sizes, int n_in,
                              void* d_out, int out_size, void* d_ws, size_t ws_size,
                              hipStream_t stream) {
    const float* x = (const float*)d_in[0];
    const float* w = (const float*)d_in[1];
    const float* b = (const float*)d_in[2];
    float* out = (float*)d_out;

    constexpr int D4 = DIM / 4;
    constexpr int NT = SEQ / TCHUNK;
    int total_threads = BATCH * NT * D4;        // 524288
    int block = 256;
    int grid = total_threads / block;           // 2048

    ShortConv1D_78855599554935_kernel<<<grid, block, 0, stream>>>(x, w, b, out);
}

// Round 3
// 236.449 us; speedup vs baseline: 1.0010x; 1.0010x over previous
//
#include <hip/hip_runtime.h>

#define DIM    2048
#define SEQ    4096
#define BATCH  4
#define KW     4
#define TCHUNK 16

typedef float fvec4 __attribute__((ext_vector_type(4)));  // native vector for builtins

// One thread: 4 consecutive channels (float4) x TCHUNK timesteps.
// Phase 1: batch-load 3 halo + TCHUNK body float4s into a register array
//          (19 independent global loads in flight -> latency hidden).
// Phase 2: compute K=4 causal stencil from registers, nontemporal stores.
__global__ __launch_bounds__(256) void ShortConv1D_78855599554935_kernel(
    const float* __restrict__ x, const float* __restrict__ w,
    const float* __restrict__ bias, float* __restrict__ out)
{
    constexpr int D4 = DIM / 4;        // 512 float4 columns
    constexpr int NT = SEQ / TCHUNK;   // 256 time chunks

    int idx  = blockIdx.x * blockDim.x + threadIdx.x;
    int d4   = idx % D4;
    int rest = idx / D4;
    int tc   = rest % NT;
    int bb   = rest / NT;

    const fvec4* __restrict__ x4 = (const fvec4*)x;
    const fvec4* __restrict__ w4 = (const fvec4*)w;
    const fvec4* __restrict__ b4 = (const fvec4*)bias;
    fvec4* __restrict__ o4 = (fvec4*)out;

    long base = ((long)bb * SEQ + (long)tc * TCHUNK) * D4 + d4;  // fvec4 units

    // ---- Phase 1: independent loads into register array ----
    fvec4 xv[TCHUNK + 3];
    if (tc > 0) {                      // wave-uniform branch (D4=512 >= 64)
        xv[0] = x4[base - 3 * D4];
        xv[1] = x4[base - 2 * D4];
        xv[2] = x4[base - 1 * D4];
    } else {
        xv[0] = (fvec4)(0.f);
        xv[1] = (fvec4)(0.f);
        xv[2] = (fvec4)(0.f);
    }
#pragma unroll
    for (int t = 0; t < TCHUNK; ++t) {
        xv[3 + t] = x4[base + t * D4];
    }

    // weight rows for channels d = 4*d4 + j  (w is [D,K] row-major, K=4)
    fvec4 w0 = w4[d4 * 4 + 0];
    fvec4 w1 = w4[d4 * 4 + 1];
    fvec4 w2 = w4[d4 * 4 + 2];
    fvec4 w3 = w4[d4 * 4 + 3];
    fvec4 bv = b4[d4];

    // ---- Phase 2: compute + streaming stores ----
#pragma unroll
    for (int t = 0; t < TCHUNK; ++t) {
        fvec4 a  = xv[t];       // x[t-3]
        fvec4 bq = xv[t + 1];   // x[t-2]
        fvec4 c  = xv[t + 2];   // x[t-1]
        fvec4 dd = xv[t + 3];   // x[t]
        fvec4 r;
        r.x = bv.x + w0.x * a.x + w0.y * bq.x + w0.z * c.x + w0.w * dd.x;
        r.y = bv.y + w1.x * a.y + w1.y * bq.y + w1.z * c.y + w1.w * dd.y;
        r.z = bv.z + w2.x * a.z + w2.y * bq.z + w2.z * c.z + w2.w * dd.z;
        r.w = bv.w + w3.x * a.w + w3.y * bq.w + w3.z * c.w + w3.w * dd.w;
        __builtin_nontemporal_store(r, &o4[base + t * D4]);
    }
}

extern "C" void kernel_launch(void* const* d_in, const int* in_sizes, int n_in,
                              void* d_out, int out_size, void* d_ws, size_t ws_size,
                              hipStream_t stream) {
    const float* x = (const float*)d_in[0];
    const float* w = (const float*)d_in[1];
    const float* b = (const float*)d_in[2];
    float* out = (float*)d_out;

    constexpr int D4 = DIM / 4;
    constexpr int NT = SEQ / TCHUNK;
    int total_threads = BATCH * NT * D4;        // 524288
    int block = 256;
    int grid = total_threads / block;           // 2048

    ShortConv1D_78855599554935_kernel<<<grid, block, 0, stream>>>(x, w, b, out);
}